// Round 3
// baseline (572.072 us; speedup 1.0000x reference)
//
#include <hip/hip_runtime.h>
#include <hip/hip_bf16.h>
#include <math.h>

#define B_ 16
#define S_ 4096
#define E_ 1024
#define H_ 512

typedef short bf16x8 __attribute__((ext_vector_type(8)));
typedef unsigned short u16x8 __attribute__((ext_vector_type(8)));
typedef float f32x4 __attribute__((ext_vector_type(4)));

__device__ inline unsigned short f2bf(float x) {
    __hip_bfloat16 h = __float2bfloat16(x);
    return *(unsigned short*)&h;
}
__device__ inline float bf2f(unsigned short u) {
    unsigned int x = ((unsigned int)u) << 16;
    float f;
    __builtin_memcpy(&f, &x, 4);
    return f;
}

// WeT[n][k] = bf16(We[k][n]);  64x64 LDS transpose tiles.
__global__ __launch_bounds__(256) void we_transpose_kernel(
    const float* __restrict__ We, unsigned short* __restrict__ WeT) {
    __shared__ float sT[64][65];
    int k0 = (blockIdx.x >> 3) * 64;
    int n0 = (blockIdx.x & 7) * 64;
    int t = threadIdx.x;
#pragma unroll
    for (int p = 0; p < 16; ++p) {
        int idx = p * 256 + t;
        int k = idx >> 6, n = idx & 63;
        sT[n][k] = We[(size_t)(k0 + k) * H_ + n0 + n];
    }
    __syncthreads();
#pragma unroll
    for (int p = 0; p < 16; ++p) {
        int idx = p * 256 + t;
        int n = idx >> 6, k = idx & 63;
        WeT[(size_t)(n0 + n) * E_ + k0 + k] = f2bf(sT[n][k]);
    }
}

// dp[b][h] = dec[b,:] . Wd[:,h] + bd[h] + be[h]   (bo dropped: softmax-invariant)
__global__ __launch_bounds__(256) void dp_kernel(const float* __restrict__ dec,
                                                 const float* __restrict__ Wd,
                                                 const float* __restrict__ bd,
                                                 const float* __restrict__ be,
                                                 float* __restrict__ dp) {
    int b = blockIdx.x >> 3;
    int hc = blockIdx.x & 7;
    int t = threadIdx.x;
    int h = hc * 64 + (t & 63);
    int ec = t >> 6;
    const float* dr = dec + b * E_ + ec * 256;
    const float* wp = Wd + (size_t)(ec * 256) * H_ + h;
    float acc = 0.f;
#pragma unroll 8
    for (int e = 0; e < 256; ++e) acc = fmaf(dr[e], wp[(size_t)e * H_], acc);
    __shared__ float red[4][64];
    red[ec][t & 63] = acc;
    __syncthreads();
    if (t < 64) {
        int hh = hc * 64 + t;
        dp[b * H_ + hh] = red[0][t] + red[1][t] + red[2][t] + red[3][t] + bd[hh] + be[hh];
    }
}

// scores[b][s] = sum_h tanh(enc@We + dp) * Wo
// Block: BM=64 s-rows x full H=512. Wave w owns n-range [w*128, w*128+128).
// enc read once; A staged bf16 in LDS (reg prefetch); B direct from global (L2).
// Optionally writes bf16 enc copy for the ctx pass.
#define BM 64
#define BK 32
#define LDA 40  // padded A row (shorts) -> <=2-way bank aliasing (free)

template <int WRITE_ENCB>
__global__ __launch_bounds__(256, 2) void scores_mfma_kernel(
    const float* __restrict__ enc, const unsigned short* __restrict__ WeT,
    const float* __restrict__ Wo, const float* __restrict__ dp,
    float* __restrict__ scores, unsigned short* __restrict__ encB) {
    __shared__ unsigned short sA[BM * LDA];
    __shared__ float sRed[4][BM];

    int tid = threadIdx.x;
    int wave = tid >> 6, lane = tid & 63;
    int quad = lane >> 4, l16 = lane & 15;
    size_t m0 = (size_t)blockIdx.x * BM;
    int b = (int)(m0 >> 12);

    // A staging map: thread covers rows (tid>>3) and (tid>>3)+32, k-off (tid&7)*4
    int srow = tid >> 3;
    int skoff = (tid & 7) * 4;
    const float* encP = enc + (m0 + srow) * E_ + skoff;
    unsigned short* encBP = encB + (m0 + srow) * E_ + skoff;
    unsigned short* sAw = sA + srow * LDA + skoff;

    f32x4 acc[4][8];
#pragma unroll
    for (int i = 0; i < 4; ++i)
#pragma unroll
        for (int j = 0; j < 8; ++j) acc[i][j] = (f32x4)0.f;

    float4 cur0 = *(const float4*)(encP);
    float4 cur1 = *(const float4*)(encP + 32 * E_);

    const unsigned short* wrow = WeT + (size_t)(wave * 128 + l16) * E_ + quad * 8;

    for (int k0 = 0; k0 < E_; k0 += BK) {
        ushort4 u0, u1;
        u0.x = f2bf(cur0.x); u0.y = f2bf(cur0.y); u0.z = f2bf(cur0.z); u0.w = f2bf(cur0.w);
        u1.x = f2bf(cur1.x); u1.y = f2bf(cur1.y); u1.z = f2bf(cur1.z); u1.w = f2bf(cur1.w);
        *(ushort4*)(sAw) = u0;
        *(ushort4*)(sAw + 32 * LDA) = u1;
        if (WRITE_ENCB) {
            *(ushort4*)(encBP + k0) = u0;
            *(ushort4*)(encBP + k0 + 32 * E_) = u1;
        }
        __syncthreads();
        if (k0 + BK < E_) {  // register prefetch of next fp32 chunk
            cur0 = *(const float4*)(encP + k0 + BK);
            cur1 = *(const float4*)(encP + k0 + BK + 32 * E_);
        }
        bf16x8 aR[4];
#pragma unroll
        for (int i = 0; i < 4; ++i)
            aR[i] = *(const bf16x8*)(sA + (i * 16 + l16) * LDA + quad * 8);
#pragma unroll
        for (int j = 0; j < 8; ++j) {
            bf16x8 bR = *(const bf16x8*)(wrow + (size_t)j * 16 * E_ + k0);
#pragma unroll
            for (int i = 0; i < 4; ++i)
                acc[i][j] = __builtin_amdgcn_mfma_f32_16x16x32_bf16(aR[i], bR, acc[i][j], 0, 0, 0);
        }
        __syncthreads();
    }

    // Epilogue: tanh(acc + dp) * Wo, reduce over the 512 h.
    float dpv[8], wov[8];
    const float* dpb = dp + b * H_;
#pragma unroll
    for (int j = 0; j < 8; ++j) {
        int h = wave * 128 + j * 16 + l16;
        dpv[j] = dpb[h];
        wov[j] = Wo[h];
    }
#pragma unroll
    for (int i = 0; i < 4; ++i)
#pragma unroll
        for (int r = 0; r < 4; ++r) {
            float s = 0.f;
#pragma unroll
            for (int j = 0; j < 8; ++j) {
                float x = acc[i][j][r] + dpv[j];
                float e = __expf(2.f * x);
                s += (1.f - 2.f / (e + 1.f)) * wov[j];
            }
            s += __shfl_xor(s, 1, 64);
            s += __shfl_xor(s, 2, 64);
            s += __shfl_xor(s, 4, 64);
            s += __shfl_xor(s, 8, 64);
            if (l16 == 0) sRed[wave][i * 16 + quad * 4 + r] = s;
        }
    __syncthreads();
    if (tid < BM) {
        int s_in = (int)(m0 & (S_ - 1)) + tid;
        scores[(size_t)b * S_ + s_in] =
            sRed[0][tid] + sRed[1][tid] + sRed[2][tid] + sRed[3][tid];
    }
}

// in-place softmax over S=4096 per batch row
__global__ __launch_bounds__(256) void softmax_kernel(float* __restrict__ sc) {
    int b = blockIdx.x;
    float* row = sc + (size_t)b * S_;
    int tid = threadIdx.x;
    float v[16];
    float m = -1e30f;
#pragma unroll
    for (int i = 0; i < 16; ++i) {
        v[i] = row[i * 256 + tid];
        m = fmaxf(m, v[i]);
    }
    for (int off = 32; off; off >>= 1) m = fmaxf(m, __shfl_xor(m, off, 64));
    __shared__ float redm[4];
    __shared__ float reds[4];
    if ((tid & 63) == 0) redm[tid >> 6] = m;
    __syncthreads();
    m = fmaxf(fmaxf(redm[0], redm[1]), fmaxf(redm[2], redm[3]));
    float s = 0.f;
#pragma unroll
    for (int i = 0; i < 16; ++i) {
        v[i] = __expf(v[i] - m);
        s += v[i];
    }
    for (int off = 32; off; off >>= 1) s += __shfl_xor(s, off, 64);
    if ((tid & 63) == 0) reds[tid >> 6] = s;
    __syncthreads();
    s = reds[0] + reds[1] + reds[2] + reds[3];
    float inv = 1.f / s;
#pragma unroll
    for (int i = 0; i < 16; ++i) row[i * 256 + tid] = v[i] * inv;
}

// ctx partials from the bf16 enc copy. Block = (b, 128-s chunk); thread owns
// 8 e-cols (16B loads), half the s-rows. 64 partials per b.
__global__ __launch_bounds__(256) void ctx_partial_bf16(
    const unsigned short* __restrict__ encB, const float* __restrict__ attn,
    float* __restrict__ part) {
    int b = blockIdx.x >> 5;
    int c = blockIdx.x & 31;
    int s0 = c * 128;
    int tid = threadIdx.x;
    __shared__ float w[128];
    if (tid < 128) w[tid] = attn[(size_t)b * S_ + s0 + tid];
    __syncthreads();
    int e8 = (tid & 127) * 8;
    int sh = tid >> 7;
    const unsigned short* base = encB + ((size_t)b * S_ + s0 + sh * 64) * E_ + e8;
    const float* wp = w + sh * 64;
    float acc[8];
#pragma unroll
    for (int t = 0; t < 8; ++t) acc[t] = 0.f;
    for (int s = 0; s < 64; s += 4) {
        u16x8 v0 = *(const u16x8*)(base + (size_t)(s + 0) * E_);
        u16x8 v1 = *(const u16x8*)(base + (size_t)(s + 1) * E_);
        u16x8 v2 = *(const u16x8*)(base + (size_t)(s + 2) * E_);
        u16x8 v3 = *(const u16x8*)(base + (size_t)(s + 3) * E_);
        float w0 = wp[s], w1 = wp[s + 1], w2 = wp[s + 2], w3 = wp[s + 3];
#pragma unroll
        for (int t = 0; t < 8; ++t) {
            acc[t] = fmaf(w0, bf2f(v0[t]), acc[t]);
            acc[t] = fmaf(w1, bf2f(v1[t]), acc[t]);
            acc[t] = fmaf(w2, bf2f(v2[t]), acc[t]);
            acc[t] = fmaf(w3, bf2f(v3[t]), acc[t]);
        }
    }
    float* po = part + ((size_t)(b * 64 + c * 2 + sh)) * E_ + e8;
    *(float4*)(po) = make_float4(acc[0], acc[1], acc[2], acc[3]);
    *(float4*)(po + 4) = make_float4(acc[4], acc[5], acc[6], acc[7]);
}

// fp32 fallback (no encB workspace): block = (b, 128-s chunk), 32 partials per b.
__global__ __launch_bounds__(256) void ctx_partial_f32(
    const float* __restrict__ enc, const float* __restrict__ attn,
    float* __restrict__ part) {
    int b = blockIdx.x >> 5;
    int c = blockIdx.x & 31;
    int s0 = c * 128;
    int tid = threadIdx.x;
    __shared__ float w[128];
    if (tid < 128) w[tid] = attn[(size_t)b * S_ + s0 + tid];
    __syncthreads();
    const float* base = enc + ((size_t)b * S_ + s0) * E_ + tid * 4;
    float4 acc = make_float4(0.f, 0.f, 0.f, 0.f);
    for (int s = 0; s < 128; s += 2) {
        float4 v0 = *(const float4*)(base + (size_t)s * E_);
        float4 v1 = *(const float4*)(base + (size_t)(s + 1) * E_);
        float w0 = w[s], w1 = w[s + 1];
        acc.x = fmaf(w0, v0.x, acc.x); acc.y = fmaf(w0, v0.y, acc.y);
        acc.z = fmaf(w0, v0.z, acc.z); acc.w = fmaf(w0, v0.w, acc.w);
        acc.x = fmaf(w1, v1.x, acc.x); acc.y = fmaf(w1, v1.y, acc.y);
        acc.z = fmaf(w1, v1.z, acc.z); acc.w = fmaf(w1, v1.w, acc.w);
    }
    *(float4*)(part + ((size_t)(b * 32 + c)) * E_ + tid * 4) = acc;
}

__global__ __launch_bounds__(256) void ctx_reduce(const float* __restrict__ part,
                                                  float* __restrict__ out, int nch) {
    int idx = blockIdx.x * 256 + threadIdx.x;  // 16*1024
    int b = idx >> 10;
    int e = idx & 1023;
    const float* p = part + (size_t)b * nch * E_ + e;
    float s = 0.f;
    for (int c = 0; c < nch; ++c) s += p[(size_t)c * E_];
    out[idx] = s;
}

extern "C" void kernel_launch(void* const* d_in, const int* in_sizes, int n_in,
                              void* d_out, int out_size, void* d_ws, size_t ws_size,
                              hipStream_t stream) {
    const float* enc = (const float*)d_in[0];  // [16,4096,1024]
    const float* dec = (const float*)d_in[1];  // [16,1024]
    const float* We  = (const float*)d_in[2];  // [1024,512]
    const float* be  = (const float*)d_in[3];  // [512]
    const float* Wd  = (const float*)d_in[4];  // [1024,512]
    const float* bd  = (const float*)d_in[5];  // [512]
    const float* Wo  = (const float*)d_in[6];  // [512,1]
    float* out = (float*)d_out;                // [16,1024]

    char* w = (char*)d_ws;
    unsigned short* WeT = (unsigned short*)w;          // 1 MiB
    float* dp = (float*)(w + (1 << 20));               // 32 KiB
    float* scores = (float*)(w + (1 << 20) + (32 << 10));  // 256 KiB
    float* part = (float*)(w + (2 << 20));             // up to 4 MiB
    unsigned short* encB = (unsigned short*)(w + (8 << 20));  // 128 MiB
    const size_t need_bf16 = (size_t)(8 << 20) + (size_t)B_ * S_ * E_ * 2;
    bool use_bf16_ctx = ws_size >= need_bf16;

    we_transpose_kernel<<<128, 256, 0, stream>>>(We, WeT);
    dp_kernel<<<B_ * 8, 256, 0, stream>>>(dec, Wd, bd, be, dp);
    if (use_bf16_ctx) {
        scores_mfma_kernel<1><<<B_ * S_ / BM, 256, 0, stream>>>(enc, WeT, Wo, dp, scores, encB);
        softmax_kernel<<<B_, 256, 0, stream>>>(scores);
        ctx_partial_bf16<<<B_ * 32, 256, 0, stream>>>(encB, scores, part);
        ctx_reduce<<<B_ * E_ / 256, 256, 0, stream>>>(part, out, 64);
    } else {
        scores_mfma_kernel<0><<<B_ * S_ / BM, 256, 0, stream>>>(enc, WeT, Wo, dp, scores, encB);
        softmax_kernel<<<B_, 256, 0, stream>>>(scores);
        ctx_partial_f32<<<B_ * 32, 256, 0, stream>>>(enc, scores, part);
        ctx_reduce<<<B_ * E_ / 256, 256, 0, stream>>>(part, out, 32);
    }
}